// Round 1
// baseline (285.139 us; speedup 1.0000x reference)
//
#include <hip/hip_runtime.h>
#include <hip/hip_bf16.h>

// ---------------------------------------------------------------------------
// EnhancedMultiHeadAttention on MI355X (gfx950)
// B=2, S=2048, D=1024, H=16, dk=64. fp32 in/out, bf16 MFMA compute.
// Pipeline: mask table -> QKV proj (bf16 MFMA) -> flash attention -> out proj.
// ws layout: qh(8MB) kh(8MB) vh(8MB) ah(8MB) mask(8KB)  => ~33.6MB needed.
// ---------------------------------------------------------------------------

#define S_LEN 2048
#define D_MODEL 1024
#define NHEADS 16
#define DK 64
#define BATCH 2
#define M_ROWS (BATCH * S_LEN)   // 4096

typedef float f32x4 __attribute__((ext_vector_type(4)));
typedef short s16x8 __attribute__((ext_vector_type(8)));

__device__ __forceinline__ unsigned short f2bf(float f) {
    unsigned u = __builtin_bit_cast(unsigned, f);
    u = (u + 0x7FFFu + ((u >> 16) & 1u)) >> 16;
    return (unsigned short)u;
}

// ---------------------------------------------------------------------------
// Mask table: m[d] = 0.25 * sum_w exp(-d^2/(2 w^2)), w in {5,10,20,40}
// ---------------------------------------------------------------------------
__global__ void mask_kernel(float* __restrict__ mtab) {
    int d = blockIdx.x * 256 + threadIdx.x;
    if (d < S_LEN) {
        float d2 = (float)d * (float)d;
        mtab[d] = 0.25f * (__expf(-d2 * (1.0f / 50.0f)) +
                           __expf(-d2 * (1.0f / 200.0f)) +
                           __expf(-d2 * (1.0f / 800.0f)) +
                           __expf(-d2 * (1.0f / 3200.0f)));
    }
}

// ---------------------------------------------------------------------------
// QKV projection: Y = X @ W^T + b  (X fp32 [4096][1024], W fp32 [1024][1024])
// Output: bf16 head layout [B][H][S][dk]; q gets *0.125 fold.
// 128x128 tile, 4 waves, BK=32, mfma_f32_16x16x32_bf16.
// ---------------------------------------------------------------------------
__global__ __launch_bounds__(256) void proj_gemm(
    const float* __restrict__ Qx, const float* __restrict__ Kx,
    const float* __restrict__ Vx,
    const float* __restrict__ Wq, const float* __restrict__ Wk,
    const float* __restrict__ Wv,
    const float* __restrict__ bq, const float* __restrict__ bk,
    const float* __restrict__ bv,
    unsigned short* __restrict__ qo, unsigned short* __restrict__ ko,
    unsigned short* __restrict__ vo)
{
    const int z = blockIdx.z;
    const float* X    = (z == 0) ? Qx : (z == 1) ? Kx : Vx;
    const float* W    = (z == 0) ? Wq : (z == 1) ? Wk : Wv;
    const float* bias = (z == 0) ? bq : (z == 1) ? bk : bv;
    unsigned short* out = (z == 0) ? qo : (z == 1) ? ko : vo;
    const float scale = (z == 0) ? 0.125f : 1.0f;

    __shared__ unsigned short As[128 * 40];  // padded stride 40 (bank spread)
    __shared__ unsigned short Bs[128 * 40];

    const int tid  = threadIdx.x;
    const int wid  = tid >> 6;
    const int lane = tid & 63;
    const int g    = lane >> 4;   // 0..3
    const int c    = lane & 15;   // 0..15
    const int wm   = wid >> 1;    // 0..1
    const int wn   = wid & 1;     // 0..1
    const int m0   = blockIdx.x * 128;
    const int n0   = blockIdx.y * 128;

    const int srow  = tid >> 1;   // 0..127
    const int shalf = tid & 1;    // 16-float half

    f32x4 acc[4][4];
#pragma unroll
    for (int i = 0; i < 4; ++i)
#pragma unroll
        for (int j = 0; j < 4; ++j) acc[i][j] = (f32x4){0.f, 0.f, 0.f, 0.f};

    for (int kt = 0; kt < D_MODEL / 32; ++kt) {
        const int k0 = kt * 32;
        __syncthreads();
        // stage A tile (fp32 -> bf16)
        {
            const float* src = X + (size_t)(m0 + srow) * D_MODEL + k0 + shalf * 16;
            f32x4 v0 = *(const f32x4*)(src + 0);
            f32x4 v1 = *(const f32x4*)(src + 4);
            f32x4 v2 = *(const f32x4*)(src + 8);
            f32x4 v3 = *(const f32x4*)(src + 12);
            s16x8 lo, hi;
#pragma unroll
            for (int j = 0; j < 4; ++j) {
                lo[j]     = (short)f2bf(v0[j]);
                lo[j + 4] = (short)f2bf(v1[j]);
                hi[j]     = (short)f2bf(v2[j]);
                hi[j + 4] = (short)f2bf(v3[j]);
            }
            *(s16x8*)&As[srow * 40 + shalf * 16]     = lo;
            *(s16x8*)&As[srow * 40 + shalf * 16 + 8] = hi;
        }
        // stage B tile (W rows are N dim; K-contiguous: B^T form)
        {
            const float* src = W + (size_t)(n0 + srow) * D_MODEL + k0 + shalf * 16;
            f32x4 v0 = *(const f32x4*)(src + 0);
            f32x4 v1 = *(const f32x4*)(src + 4);
            f32x4 v2 = *(const f32x4*)(src + 8);
            f32x4 v3 = *(const f32x4*)(src + 12);
            s16x8 lo, hi;
#pragma unroll
            for (int j = 0; j < 4; ++j) {
                lo[j]     = (short)f2bf(v0[j]);
                lo[j + 4] = (short)f2bf(v1[j]);
                hi[j]     = (short)f2bf(v2[j]);
                hi[j + 4] = (short)f2bf(v3[j]);
            }
            *(s16x8*)&Bs[srow * 40 + shalf * 16]     = lo;
            *(s16x8*)&Bs[srow * 40 + shalf * 16 + 8] = hi;
        }
        __syncthreads();

        s16x8 a[4];
#pragma unroll
        for (int mf = 0; mf < 4; ++mf)
            a[mf] = *(const s16x8*)&As[(wm * 64 + mf * 16 + c) * 40 + g * 8];
#pragma unroll
        for (int nf = 0; nf < 4; ++nf) {
            s16x8 b = *(const s16x8*)&Bs[(wn * 64 + nf * 16 + c) * 40 + g * 8];
#pragma unroll
            for (int mf = 0; mf < 4; ++mf)
                acc[mf][nf] = __builtin_amdgcn_mfma_f32_16x16x32_bf16(
                    a[mf], b, acc[mf][nf], 0, 0, 0);
        }
    }

    // epilogue: bias, scale, bf16, head layout [B][H][S][dk]
#pragma unroll
    for (int mf = 0; mf < 4; ++mf) {
#pragma unroll
        for (int nf = 0; nf < 4; ++nf) {
            const int o = n0 + wn * 64 + nf * 16 + c;
            const float bv_ = bias[o];
            const int h  = o >> 6;
            const int dd = o & 63;
#pragma unroll
            for (int r = 0; r < 4; ++r) {
                const int m = m0 + wm * 64 + mf * 16 + g * 4 + r;
                const int b = m >> 11;
                const int s = m & (S_LEN - 1);
                const float val = (acc[mf][nf][r] + bv_) * scale;
                out[(((size_t)(b * NHEADS + h)) * S_LEN + s) * DK + dd] = f2bf(val);
            }
        }
    }
}

// ---------------------------------------------------------------------------
// Flash attention: grid (S/64, B*H). 4 waves/block, 16 q-rows/wave, KBLK=64.
// scores = q@k^T (scale folded into q) + mask[i-j]; online softmax; P@V.
// ---------------------------------------------------------------------------
__global__ __launch_bounds__(256) void attn_kernel(
    const unsigned short* __restrict__ qh,
    const unsigned short* __restrict__ kh,
    const unsigned short* __restrict__ vh,
    const float* __restrict__ mask_tab,
    unsigned short* __restrict__ attn_out)
{
    __shared__ float mtab[S_LEN];                 // 8 KB
    __shared__ unsigned short Kt[64 * 64];        // 8 KB, swizzled rows
    __shared__ unsigned short Vt[64 * 64];        // 8 KB, transposed [d][k], swizzled
    __shared__ unsigned short Pt[4][16 * 64];     // 8 KB, per-wave P, swizzled

    const int tid  = threadIdx.x;
    const int wid  = tid >> 6;
    const int lane = tid & 63;
    const int g    = lane >> 4;
    const int c    = lane & 15;
    const int bh   = blockIdx.y;          // 0..31
    const int b    = bh >> 4;
    const int h    = bh & 15;
    const int q0   = blockIdx.x * 64 + wid * 16;  // wave's q base

    // mask table -> LDS
    {
        f32x4 t0 = *(const f32x4*)&mask_tab[tid * 8];
        f32x4 t1 = *(const f32x4*)&mask_tab[tid * 8 + 4];
        *(f32x4*)&mtab[tid * 8]     = t0;
        *(f32x4*)&mtab[tid * 8 + 4] = t1;
    }

    const size_t head_off = (size_t)bh * S_LEN * DK;
    const unsigned short* qp = qh + head_off;
    const unsigned short* kp = kh + head_off;
    const unsigned short* vp = vh + head_off;

    // q fragments held in registers for whole kernel
    s16x8 aq[2];
    {
        const unsigned short* qrow = qp + (size_t)(q0 + c) * DK;
        aq[0] = *(const s16x8*)(qrow + g * 8);
        aq[1] = *(const s16x8*)(qrow + 32 + g * 8);
    }

    f32x4 acc_o[4];
#pragma unroll
    for (int nf = 0; nf < 4; ++nf) acc_o[nf] = (f32x4){0.f, 0.f, 0.f, 0.f};
    float m_r[4], l_r[4];
#pragma unroll
    for (int r = 0; r < 4; ++r) { m_r[r] = -1e30f; l_r[r] = 0.f; }

    const int s_row = tid >> 2;   // staging row 0..63
    const int s_qc  = tid & 3;    // 16-col quarter

    for (int kt = 0; kt < S_LEN / 64; ++kt) {
        const int k0 = kt * 64;
        __syncthreads();
        // stage K tile [64][64], XOR-swizzled rows (128B rows)
        {
            const unsigned short* src = kp + (size_t)(k0 + s_row) * DK + s_qc * 16;
            s16x8 v0 = *(const s16x8*)(src);
            s16x8 v1 = *(const s16x8*)(src + 8);
            const int sw = (s_row & 7) << 4;
            char* base = (char*)Kt + s_row * 128;
            *(s16x8*)(base + ((s_qc * 32) ^ sw))      = v0;
            *(s16x8*)(base + ((s_qc * 32 + 16) ^ sw)) = v1;
        }
        // stage V^T tile: Vt[d][k] = v[k][d], XOR-swizzled rows
        {
            const unsigned short* src = vp + (size_t)(k0 + s_row) * DK + s_qc * 16;
            s16x8 v0 = *(const s16x8*)(src);
            s16x8 v1 = *(const s16x8*)(src + 8);
#pragma unroll
            for (int j = 0; j < 8; ++j) {
                int d0 = s_qc * 16 + j;
                int d1 = d0 + 8;
                *(unsigned short*)((char*)Vt + d0 * 128 + ((s_row * 2) ^ ((d0 & 7) << 4))) =
                    (unsigned short)v0[j];
                *(unsigned short*)((char*)Vt + d1 * 128 + ((s_row * 2) ^ ((d1 & 7) << 4))) =
                    (unsigned short)v1[j];
            }
        }
        __syncthreads();

        // QK^T: S_tile[16 q][64 k] per wave
        f32x4 s_acc[4];
#pragma unroll
        for (int nf = 0; nf < 4; ++nf) {
            s_acc[nf] = (f32x4){0.f, 0.f, 0.f, 0.f};
#pragma unroll
            for (int f = 0; f < 2; ++f) {
                const int row = nf * 16 + c;
                s16x8 bk = *(const s16x8*)((const char*)Kt + row * 128 +
                                           ((f * 64 + g * 16) ^ ((row & 7) << 4)));
                s_acc[nf] = __builtin_amdgcn_mfma_f32_16x16x32_bf16(
                    aq[f], bk, s_acc[nf], 0, 0, 0);
            }
        }

        // mask add + tile row-max
        float tmax[4] = {-1e30f, -1e30f, -1e30f, -1e30f};
#pragma unroll
        for (int nf = 0; nf < 4; ++nf) {
            const int j_glob = k0 + nf * 16 + c;
#pragma unroll
            for (int r = 0; r < 4; ++r) {
                const int i_glob = q0 + g * 4 + r;
                const int dd = i_glob - j_glob;
                const float mv = (dd >= 0) ? mtab[dd] : 0.f;
                const float sv = s_acc[nf][r] + mv;
                s_acc[nf][r] = sv;
                tmax[r] = fmaxf(tmax[r], sv);
            }
        }
#pragma unroll
        for (int r = 0; r < 4; ++r) {
            tmax[r] = fmaxf(tmax[r], __shfl_xor(tmax[r], 1));
            tmax[r] = fmaxf(tmax[r], __shfl_xor(tmax[r], 2));
            tmax[r] = fmaxf(tmax[r], __shfl_xor(tmax[r], 4));
            tmax[r] = fmaxf(tmax[r], __shfl_xor(tmax[r], 8));
        }

        float csc[4], p_sum[4];
#pragma unroll
        for (int r = 0; r < 4; ++r) {
            const float mnew = fmaxf(m_r[r], tmax[r]);
            csc[r] = __expf(m_r[r] - mnew);
            m_r[r] = mnew;
            p_sum[r] = 0.f;
        }
#pragma unroll
        for (int nf = 0; nf < 4; ++nf)
#pragma unroll
            for (int r = 0; r < 4; ++r) {
                const float p = __expf(s_acc[nf][r] - m_r[r]);
                s_acc[nf][r] = p;
                p_sum[r] += p;
            }
#pragma unroll
        for (int r = 0; r < 4; ++r) {
            p_sum[r] += __shfl_xor(p_sum[r], 1);
            p_sum[r] += __shfl_xor(p_sum[r], 2);
            p_sum[r] += __shfl_xor(p_sum[r], 4);
            p_sum[r] += __shfl_xor(p_sum[r], 8);
            l_r[r] = l_r[r] * csc[r] + p_sum[r];
        }
#pragma unroll
        for (int nf = 0; nf < 4; ++nf)
#pragma unroll
            for (int r = 0; r < 4; ++r) acc_o[nf][r] *= csc[r];

        // write P (bf16) to per-wave swizzled LDS tile
        unsigned short* pw = Pt[wid];
#pragma unroll
        for (int nf = 0; nf < 4; ++nf) {
            const int col = nf * 16 + c;
#pragma unroll
            for (int r = 0; r < 4; ++r) {
                const int qr = g * 4 + r;
                *(unsigned short*)((char*)pw + qr * 128 +
                                   ((col * 2) ^ ((qr & 7) << 4))) = f2bf(s_acc[nf][r]);
            }
        }
        // PV: O += P @ V  (same-wave DS ops are in-order; no barrier needed)
#pragma unroll
        for (int f = 0; f < 2; ++f) {
            s16x8 ap = *(const s16x8*)((const char*)pw + c * 128 +
                                       ((f * 64 + g * 16) ^ ((c & 7) << 4)));
#pragma unroll
            for (int nf = 0; nf < 4; ++nf) {
                const int row = nf * 16 + c;
                s16x8 bv = *(const s16x8*)((const char*)Vt + row * 128 +
                                           ((f * 64 + g * 16) ^ ((row & 7) << 4)));
                acc_o[nf] = __builtin_amdgcn_mfma_f32_16x16x32_bf16(
                    ap, bv, acc_o[nf], 0, 0, 0);
            }
        }
    }

    // epilogue: normalize, store bf16 to [B][S][D] row layout
#pragma unroll
    for (int nf = 0; nf < 4; ++nf) {
#pragma unroll
        for (int r = 0; r < 4; ++r) {
            const int i_glob = q0 + g * 4 + r;
            const int d = nf * 16 + c;
            const float o = acc_o[nf][r] / l_r[r];
            attn_out[((size_t)(b * S_LEN + i_glob)) * D_MODEL + h * DK + d] = f2bf(o);
        }
    }
}

// ---------------------------------------------------------------------------
// Output projection: Y = A @ Wo^T + bo  (A bf16 [4096][1024], out fp32)
// ---------------------------------------------------------------------------
__global__ __launch_bounds__(256) void out_gemm(
    const unsigned short* __restrict__ A,
    const float* __restrict__ W,
    const float* __restrict__ bias,
    float* __restrict__ out)
{
    __shared__ unsigned short As[128 * 40];
    __shared__ unsigned short Bs[128 * 40];

    const int tid  = threadIdx.x;
    const int wid  = tid >> 6;
    const int lane = tid & 63;
    const int g    = lane >> 4;
    const int c    = lane & 15;
    const int wm   = wid >> 1;
    const int wn   = wid & 1;
    const int m0   = blockIdx.x * 128;
    const int n0   = blockIdx.y * 128;

    const int srow  = tid >> 1;
    const int shalf = tid & 1;

    f32x4 acc[4][4];
#pragma unroll
    for (int i = 0; i < 4; ++i)
#pragma unroll
        for (int j = 0; j < 4; ++j) acc[i][j] = (f32x4){0.f, 0.f, 0.f, 0.f};

    for (int kt = 0; kt < D_MODEL / 32; ++kt) {
        const int k0 = kt * 32;
        __syncthreads();
        // stage A (already bf16)
        {
            const unsigned short* src =
                A + (size_t)(m0 + srow) * D_MODEL + k0 + shalf * 16;
            s16x8 lo = *(const s16x8*)(src);
            s16x8 hi = *(const s16x8*)(src + 8);
            *(s16x8*)&As[srow * 40 + shalf * 16]     = lo;
            *(s16x8*)&As[srow * 40 + shalf * 16 + 8] = hi;
        }
        // stage B (fp32 -> bf16)
        {
            const float* src = W + (size_t)(n0 + srow) * D_MODEL + k0 + shalf * 16;
            f32x4 v0 = *(const f32x4*)(src + 0);
            f32x4 v1 = *(const f32x4*)(src + 4);
            f32x4 v2 = *(const f32x4*)(src + 8);
            f32x4 v3 = *(const f32x4*)(src + 12);
            s16x8 lo, hi;
#pragma unroll
            for (int j = 0; j < 4; ++j) {
                lo[j]     = (short)f2bf(v0[j]);
                lo[j + 4] = (short)f2bf(v1[j]);
                hi[j]     = (short)f2bf(v2[j]);
                hi[j + 4] = (short)f2bf(v3[j]);
            }
            *(s16x8*)&Bs[srow * 40 + shalf * 16]     = lo;
            *(s16x8*)&Bs[srow * 40 + shalf * 16 + 8] = hi;
        }
        __syncthreads();

        s16x8 a[4];
#pragma unroll
        for (int mf = 0; mf < 4; ++mf)
            a[mf] = *(const s16x8*)&As[(wm * 64 + mf * 16 + c) * 40 + g * 8];
#pragma unroll
        for (int nf = 0; nf < 4; ++nf) {
            s16x8 b = *(const s16x8*)&Bs[(wn * 64 + nf * 16 + c) * 40 + g * 8];
#pragma unroll
            for (int mf = 0; mf < 4; ++mf)
                acc[mf][nf] = __builtin_amdgcn_mfma_f32_16x16x32_bf16(
                    a[mf], b, acc[mf][nf], 0, 0, 0);
        }
    }

#pragma unroll
    for (int mf = 0; mf < 4; ++mf) {
#pragma unroll
        for (int nf = 0; nf < 4; ++nf) {
            const int o = n0 + wn * 64 + nf * 16 + c;
            const float bv_ = bias[o];
#pragma unroll
            for (int r = 0; r < 4; ++r) {
                const int m = m0 + wm * 64 + mf * 16 + g * 4 + r;
                out[(size_t)m * D_MODEL + o] = acc[mf][nf][r] + bv_;
            }
        }
    }
}

// ---------------------------------------------------------------------------
extern "C" void kernel_launch(void* const* d_in, const int* in_sizes, int n_in,
                              void* d_out, int out_size, void* d_ws, size_t ws_size,
                              hipStream_t stream) {
    const float* Q  = (const float*)d_in[0];
    const float* K  = (const float*)d_in[1];
    const float* V  = (const float*)d_in[2];
    const float* Wq = (const float*)d_in[3];
    const float* bq = (const float*)d_in[4];
    const float* Wk = (const float*)d_in[5];
    const float* bk = (const float*)d_in[6];
    const float* Wv = (const float*)d_in[7];
    const float* bv = (const float*)d_in[8];
    const float* Wo = (const float*)d_in[9];
    const float* bo = (const float*)d_in[10];
    float* out = (float*)d_out;

    // ws carve-up (~33.6 MB)
    const size_t HEAD_ELEMS = (size_t)BATCH * NHEADS * S_LEN * DK;  // 4.19M
    unsigned short* qh = (unsigned short*)d_ws;
    unsigned short* kh = qh + HEAD_ELEMS;
    unsigned short* vh = kh + HEAD_ELEMS;
    unsigned short* ah = vh + HEAD_ELEMS;
    float* mtab = (float*)(ah + HEAD_ELEMS);

    mask_kernel<<<dim3(S_LEN / 256), 256, 0, stream>>>(mtab);
    proj_gemm<<<dim3(M_ROWS / 128, D_MODEL / 128, 3), 256, 0, stream>>>(
        Q, K, V, Wq, Wk, Wv, bq, bk, bv, qh, kh, vh);
    attn_kernel<<<dim3(S_LEN / 64, BATCH * NHEADS), 256, 0, stream>>>(
        qh, kh, vh, mtab, ah);
    out_gemm<<<dim3(M_ROWS / 128, D_MODEL / 128), 256, 0, stream>>>(
        ah, Wo, bo, out);
}

// Round 2
// 203.329 us; speedup vs baseline: 1.4024x; 1.4024x over previous
//
#include <hip/hip_runtime.h>
#include <hip/hip_bf16.h>

// ---------------------------------------------------------------------------
// EnhancedMultiHeadAttention on MI355X (gfx950)
// B=2, S=2048, D=1024, H=16, dk=64. fp32 in/out, bf16 MFMA compute.
// Round 2: attention reworked — swapped QK^T (S^T layout -> lane-local q),
// vectorized V-transpose staging, vectorized P stores, mask tile-skip,
// exp2 domain, 8-wave blocks with register prefetch of next K/V tile.
// ---------------------------------------------------------------------------

#define S_LEN 2048
#define D_MODEL 1024
#define NHEADS 16
#define DK 64
#define BATCH 2
#define M_ROWS (BATCH * S_LEN)   // 4096
#define LOG2E 1.4426950408889634f

typedef float f32x4 __attribute__((ext_vector_type(4)));
typedef short s16x8 __attribute__((ext_vector_type(8)));
typedef unsigned short u16x4 __attribute__((ext_vector_type(4)));

__device__ __forceinline__ unsigned short f2bf(float f) {
    unsigned u = __builtin_bit_cast(unsigned, f);
    u = (u + 0x7FFFu + ((u >> 16) & 1u)) >> 16;
    return (unsigned short)u;
}

__device__ __forceinline__ float fast_exp2(float x) {
    float r;
    asm("v_exp_f32 %0, %1" : "=v"(r) : "v"(x));
    return r;
}

// ---------------------------------------------------------------------------
// Mask table in exp2 domain: m[d] = log2e * 0.25 * sum_w exp(-d^2/(2 w^2))
// ---------------------------------------------------------------------------
__global__ void mask_kernel(float* __restrict__ mtab) {
    int d = blockIdx.x * 256 + threadIdx.x;
    if (d < S_LEN) {
        float d2 = (float)d * (float)d;
        mtab[d] = LOG2E * 0.25f * (__expf(-d2 * (1.0f / 50.0f)) +
                                   __expf(-d2 * (1.0f / 200.0f)) +
                                   __expf(-d2 * (1.0f / 800.0f)) +
                                   __expf(-d2 * (1.0f / 3200.0f)));
    }
}

// ---------------------------------------------------------------------------
// QKV projection: Y = X @ W^T + b. Output bf16 head layout [B][H][S][dk];
// q gets *(0.125*log2e) fold (exp2-domain softmax).
// ---------------------------------------------------------------------------
__global__ __launch_bounds__(256) void proj_gemm(
    const float* __restrict__ Qx, const float* __restrict__ Kx,
    const float* __restrict__ Vx,
    const float* __restrict__ Wq, const float* __restrict__ Wk,
    const float* __restrict__ Wv,
    const float* __restrict__ bq, const float* __restrict__ bk,
    const float* __restrict__ bv,
    unsigned short* __restrict__ qo, unsigned short* __restrict__ ko,
    unsigned short* __restrict__ vo)
{
    const int z = blockIdx.z;
    const float* X    = (z == 0) ? Qx : (z == 1) ? Kx : Vx;
    const float* W    = (z == 0) ? Wq : (z == 1) ? Wk : Wv;
    const float* bias = (z == 0) ? bq : (z == 1) ? bk : bv;
    unsigned short* out = (z == 0) ? qo : (z == 1) ? ko : vo;
    const float scale = (z == 0) ? (0.125f * LOG2E) : 1.0f;

    __shared__ unsigned short As[128 * 40];
    __shared__ unsigned short Bs[128 * 40];

    const int tid  = threadIdx.x;
    const int wid  = tid >> 6;
    const int lane = tid & 63;
    const int g    = lane >> 4;
    const int c    = lane & 15;
    const int wm   = wid >> 1;
    const int wn   = wid & 1;
    const int m0   = blockIdx.x * 128;
    const int n0   = blockIdx.y * 128;

    const int srow  = tid >> 1;
    const int shalf = tid & 1;

    f32x4 acc[4][4];
#pragma unroll
    for (int i = 0; i < 4; ++i)
#pragma unroll
        for (int j = 0; j < 4; ++j) acc[i][j] = (f32x4){0.f, 0.f, 0.f, 0.f};

    for (int kt = 0; kt < D_MODEL / 32; ++kt) {
        const int k0 = kt * 32;
        __syncthreads();
        {
            const float* src = X + (size_t)(m0 + srow) * D_MODEL + k0 + shalf * 16;
            f32x4 v0 = *(const f32x4*)(src + 0);
            f32x4 v1 = *(const f32x4*)(src + 4);
            f32x4 v2 = *(const f32x4*)(src + 8);
            f32x4 v3 = *(const f32x4*)(src + 12);
            s16x8 lo, hi;
#pragma unroll
            for (int j = 0; j < 4; ++j) {
                lo[j]     = (short)f2bf(v0[j]);
                lo[j + 4] = (short)f2bf(v1[j]);
                hi[j]     = (short)f2bf(v2[j]);
                hi[j + 4] = (short)f2bf(v3[j]);
            }
            *(s16x8*)&As[srow * 40 + shalf * 16]     = lo;
            *(s16x8*)&As[srow * 40 + shalf * 16 + 8] = hi;
        }
        {
            const float* src = W + (size_t)(n0 + srow) * D_MODEL + k0 + shalf * 16;
            f32x4 v0 = *(const f32x4*)(src + 0);
            f32x4 v1 = *(const f32x4*)(src + 4);
            f32x4 v2 = *(const f32x4*)(src + 8);
            f32x4 v3 = *(const f32x4*)(src + 12);
            s16x8 lo, hi;
#pragma unroll
            for (int j = 0; j < 4; ++j) {
                lo[j]     = (short)f2bf(v0[j]);
                lo[j + 4] = (short)f2bf(v1[j]);
                hi[j]     = (short)f2bf(v2[j]);
                hi[j + 4] = (short)f2bf(v3[j]);
            }
            *(s16x8*)&Bs[srow * 40 + shalf * 16]     = lo;
            *(s16x8*)&Bs[srow * 40 + shalf * 16 + 8] = hi;
        }
        __syncthreads();

        s16x8 a[4];
#pragma unroll
        for (int mf = 0; mf < 4; ++mf)
            a[mf] = *(const s16x8*)&As[(wm * 64 + mf * 16 + c) * 40 + g * 8];
#pragma unroll
        for (int nf = 0; nf < 4; ++nf) {
            s16x8 b = *(const s16x8*)&Bs[(wn * 64 + nf * 16 + c) * 40 + g * 8];
#pragma unroll
            for (int mf = 0; mf < 4; ++mf)
                acc[mf][nf] = __builtin_amdgcn_mfma_f32_16x16x32_bf16(
                    a[mf], b, acc[mf][nf], 0, 0, 0);
        }
    }

#pragma unroll
    for (int mf = 0; mf < 4; ++mf) {
#pragma unroll
        for (int nf = 0; nf < 4; ++nf) {
            const int o = n0 + wn * 64 + nf * 16 + c;
            const float bv_ = bias[o];
            const int h  = o >> 6;
            const int dd = o & 63;
#pragma unroll
            for (int r = 0; r < 4; ++r) {
                const int m = m0 + wm * 64 + mf * 16 + g * 4 + r;
                const int b = m >> 11;
                const int s = m & (S_LEN - 1);
                const float val = (acc[mf][nf][r] + bv_) * scale;
                out[(((size_t)(b * NHEADS + h)) * S_LEN + s) * DK + dd] = f2bf(val);
            }
        }
    }
}

// ---------------------------------------------------------------------------
// Flash attention, swapped-QK^T structure.
// grid (S/128, B*H), 8 waves/block, 16 q-rows/wave, KBLK=64.
// S^T = mfma(K, Q): lane holds q = lane&15, k = nf*16+g*4+r  -> lane-local
// softmax row state, b64 P stores, 2-shuffle reductions.
// ---------------------------------------------------------------------------
__global__ __launch_bounds__(512) void attn_kernel(
    const unsigned short* __restrict__ qh,
    const unsigned short* __restrict__ kh,
    const unsigned short* __restrict__ vh,
    const float* __restrict__ mask_tab,
    unsigned short* __restrict__ attn_out)
{
    __shared__ float mtab[S_LEN];                 // 8 KB (log2e-scaled)
    __shared__ unsigned short Kt[64 * 64];        // 8 KB, XOR-swizzled rows
    __shared__ unsigned short Vt[64 * 64];        // 8 KB, transposed [d][k], swizzled
    __shared__ unsigned short Pt[8][16 * 64];     // 16 KB, per-wave P

    const int tid  = threadIdx.x;
    const int wid  = tid >> 6;
    const int lane = tid & 63;
    const int g    = lane >> 4;
    const int c    = lane & 15;
    const int bh   = blockIdx.y;
    const int b    = bh >> 4;
    const int h    = bh & 15;
    const int q0w  = blockIdx.x * 128 + wid * 16;

    // mask table -> LDS (512 threads x 4 floats)
    *(f32x4*)&mtab[tid * 4] = *(const f32x4*)&mask_tab[tid * 4];

    const size_t head_off = (size_t)bh * S_LEN * DK;
    const unsigned short* qp = qh + head_off;
    const unsigned short* kp = kh + head_off;
    const unsigned short* vp = vh + head_off;

    // Q fragments (B-operand of swapped QK^T) in registers for whole kernel
    s16x8 aq[2];
    {
        const unsigned short* qrow = qp + (size_t)(q0w + c) * DK;
        aq[0] = *(const s16x8*)(qrow + g * 8);
        aq[1] = *(const s16x8*)(qrow + 32 + g * 8);
    }

    f32x4 acc_o[4];
#pragma unroll
    for (int nf = 0; nf < 4; ++nf) acc_o[nf] = (f32x4){0.f, 0.f, 0.f, 0.f};
    float m_l = -1e30f, l_l = 0.f;   // per-lane softmax state for q = q0w + c

    // staging decomposition (512 threads)
    const int srowK = tid >> 3;          // K: row 0..63
    const int soffE = (tid & 7) * 8;     // K: element offset in row
    const int vd0   = (tid & 31) * 2;    // V: d row pair 0..62
    const int vkq   = (tid >> 5) * 4;    // V: k quad 0..60

    // prefetch tile 0 into registers
    s16x8 kreg;
    unsigned vreg[4];
    kreg = *(const s16x8*)&kp[(size_t)srowK * DK + soffE];
#pragma unroll
    for (int i = 0; i < 4; ++i)
        vreg[i] = *(const unsigned*)&vp[(size_t)(vkq + i) * DK + vd0];

    unsigned short* Ptw = Pt[wid];

    for (int kt = 0; kt < S_LEN / 64; ++kt) {
        const int k0 = kt * 64;
        __syncthreads();   // previous tile's LDS reads done

        // ---- write staged registers to LDS ----
        *(s16x8*)((char*)Kt + srowK * 128 + ((soffE * 2) ^ ((srowK & 7) << 4))) = kreg;
        {
            u16x4 lo4, hi4;
#pragma unroll
            for (int i = 0; i < 4; ++i) {
                lo4[i] = (unsigned short)vreg[i];
                hi4[i] = (unsigned short)(vreg[i] >> 16);
            }
            *(u16x4*)((char*)Vt + vd0 * 128 + ((vkq * 2) ^ ((vd0 & 7) << 4))) = lo4;
            *(u16x4*)((char*)Vt + (vd0 + 1) * 128 +
                      ((vkq * 2) ^ (((vd0 + 1) & 7) << 4))) = hi4;
        }
        // ---- prefetch next tile (latency hides under compute below) ----
        if (kt < S_LEN / 64 - 1) {
            const int k1 = k0 + 64;
            kreg = *(const s16x8*)&kp[(size_t)(k1 + srowK) * DK + soffE];
#pragma unroll
            for (int i = 0; i < 4; ++i)
                vreg[i] = *(const unsigned*)&vp[(size_t)(k1 + vkq + i) * DK + vd0];
        }
        __syncthreads();   // staging visible

        // ---- QK^T (swapped): S^T[k][q], lane holds q=c, k = nf*16+g*4+r ----
        f32x4 st[4];
#pragma unroll
        for (int nf = 0; nf < 4; ++nf) {
            st[nf] = (f32x4){0.f, 0.f, 0.f, 0.f};
#pragma unroll
            for (int f = 0; f < 2; ++f) {
                const int row = nf * 16 + c;
                s16x8 kf = *(const s16x8*)((const char*)Kt + row * 128 +
                                           ((f * 64 + g * 16) ^ ((row & 7) << 4)));
                st[nf] = __builtin_amdgcn_mfma_f32_16x16x32_bf16(
                    kf, aq[f], st[nf], 0, 0, 0);
            }
        }

        // ---- mask add (only near-diagonal tiles matter: mask < 1e-20 beyond) ----
        const int diff = q0w - k0;
        if (diff >= -15 && diff <= 510) {
            const int dbase = q0w + c - k0;
#pragma unroll
            for (int nf = 0; nf < 4; ++nf) {
#pragma unroll
                for (int r = 0; r < 4; ++r) {
                    const int d = dbase - (nf * 16 + g * 4 + r);
                    if (d >= 0) st[nf][r] += mtab[d];
                }
            }
        }

        // ---- online softmax (lane-local row; reduce over 4 g-lanes) ----
        float tm = -1e30f;
#pragma unroll
        for (int nf = 0; nf < 4; ++nf)
#pragma unroll
            for (int r = 0; r < 4; ++r) tm = fmaxf(tm, st[nf][r]);
        tm = fmaxf(tm, __shfl_xor(tm, 16));
        tm = fmaxf(tm, __shfl_xor(tm, 32));

        const float mnew = fmaxf(m_l, tm);
        const float csc  = fast_exp2(m_l - mnew);
        m_l = mnew;

        float ps = 0.f;
#pragma unroll
        for (int nf = 0; nf < 4; ++nf)
#pragma unroll
            for (int r = 0; r < 4; ++r) {
                const float p = fast_exp2(st[nf][r] - mnew);
                st[nf][r] = p;
                ps += p;
            }
        ps += __shfl_xor(ps, 16);
        ps += __shfl_xor(ps, 32);
        l_l = l_l * csc + ps;

        // rescale factors for acc_o rows (q = g*4 + r lives at lane c = g*4+r)
        float cscq[4];
#pragma unroll
        for (int r = 0; r < 4; ++r) cscq[r] = __shfl(csc, g * 4 + r);
#pragma unroll
        for (int nf = 0; nf < 4; ++nf)
#pragma unroll
            for (int r = 0; r < 4; ++r) acc_o[nf][r] *= cscq[r];

        // ---- P store: lane-contiguous k -> one b64 per nf ----
#pragma unroll
        for (int nf = 0; nf < 4; ++nf) {
            u16x4 pk;
#pragma unroll
            for (int r = 0; r < 4; ++r) pk[r] = f2bf(st[nf][r]);
            *(u16x4*)((char*)Ptw + c * 128 +
                      ((nf * 32 + g * 8) ^ ((c & 7) << 4))) = pk;
        }

        // ---- PV: O[q][d] += P @ V  (same-wave LDS; compiler orders via lgkmcnt)
#pragma unroll
        for (int f = 0; f < 2; ++f) {
            s16x8 pa = *(const s16x8*)((const char*)Ptw + c * 128 +
                                       ((f * 64 + g * 16) ^ ((c & 7) << 4)));
#pragma unroll
            for (int nf = 0; nf < 4; ++nf) {
                const int row = nf * 16 + c;
                s16x8 vb = *(const s16x8*)((const char*)Vt + row * 128 +
                                           ((f * 64 + g * 16) ^ ((row & 7) << 4)));
                acc_o[nf] = __builtin_amdgcn_mfma_f32_16x16x32_bf16(
                    pa, vb, acc_o[nf], 0, 0, 0);
            }
        }
    }

    // epilogue: normalize (l for q=g*4+r lives at lane c=g*4+r), store bf16
    float lq[4];
#pragma unroll
    for (int r = 0; r < 4; ++r) lq[r] = __shfl(l_l, g * 4 + r);
#pragma unroll
    for (int nf = 0; nf < 4; ++nf) {
#pragma unroll
        for (int r = 0; r < 4; ++r) {
            const int i_glob = q0w + g * 4 + r;
            const int d = nf * 16 + c;
            const float o = acc_o[nf][r] / lq[r];
            attn_out[((size_t)(b * S_LEN + i_glob)) * D_MODEL + h * DK + d] = f2bf(o);
        }
    }
}

// ---------------------------------------------------------------------------
// Output projection: Y = A @ Wo^T + bo  (A bf16 [4096][1024], out fp32)
// ---------------------------------------------------------------------------
__global__ __launch_bounds__(256) void out_gemm(
    const unsigned short* __restrict__ A,
    const float* __restrict__ W,
    const float* __restrict__ bias,
    float* __restrict__ out)
{
    __shared__ unsigned short As[128 * 40];
    __shared__ unsigned short Bs[128 * 40];

    const int tid  = threadIdx.x;
    const int wid  = tid >> 6;
    const int lane = tid & 63;
    const int g    = lane >> 4;
    const int c    = lane & 15;
    const int wm   = wid >> 1;
    const int wn   = wid & 1;
    const int m0   = blockIdx.x * 128;
    const int n0   = blockIdx.y * 128;

    const int srow  = tid >> 1;
    const int shalf = tid & 1;

    f32x4 acc[4][4];
#pragma unroll
    for (int i = 0; i < 4; ++i)
#pragma unroll
        for (int j = 0; j < 4; ++j) acc[i][j] = (f32x4){0.f, 0.f, 0.f, 0.f};

    for (int kt = 0; kt < D_MODEL / 32; ++kt) {
        const int k0 = kt * 32;
        __syncthreads();
        {
            const unsigned short* src =
                A + (size_t)(m0 + srow) * D_MODEL + k0 + shalf * 16;
            s16x8 lo = *(const s16x8*)(src);
            s16x8 hi = *(const s16x8*)(src + 8);
            *(s16x8*)&As[srow * 40 + shalf * 16]     = lo;
            *(s16x8*)&As[srow * 40 + shalf * 16 + 8] = hi;
        }
        {
            const float* src = W + (size_t)(n0 + srow) * D_MODEL + k0 + shalf * 16;
            f32x4 v0 = *(const f32x4*)(src + 0);
            f32x4 v1 = *(const f32x4*)(src + 4);
            f32x4 v2 = *(const f32x4*)(src + 8);
            f32x4 v3 = *(const f32x4*)(src + 12);
            s16x8 lo, hi;
#pragma unroll
            for (int j = 0; j < 4; ++j) {
                lo[j]     = (short)f2bf(v0[j]);
                lo[j + 4] = (short)f2bf(v1[j]);
                hi[j]     = (short)f2bf(v2[j]);
                hi[j + 4] = (short)f2bf(v3[j]);
            }
            *(s16x8*)&Bs[srow * 40 + shalf * 16]     = lo;
            *(s16x8*)&Bs[srow * 40 + shalf * 16 + 8] = hi;
        }
        __syncthreads();

        s16x8 a[4];
#pragma unroll
        for (int mf = 0; mf < 4; ++mf)
            a[mf] = *(const s16x8*)&As[(wm * 64 + mf * 16 + c) * 40 + g * 8];
#pragma unroll
        for (int nf = 0; nf < 4; ++nf) {
            s16x8 b = *(const s16x8*)&Bs[(wn * 64 + nf * 16 + c) * 40 + g * 8];
#pragma unroll
            for (int mf = 0; mf < 4; ++mf)
                acc[mf][nf] = __builtin_amdgcn_mfma_f32_16x16x32_bf16(
                    a[mf], b, acc[mf][nf], 0, 0, 0);
        }
    }

#pragma unroll
    for (int mf = 0; mf < 4; ++mf) {
#pragma unroll
        for (int nf = 0; nf < 4; ++nf) {
            const int o = n0 + wn * 64 + nf * 16 + c;
            const float bv_ = bias[o];
#pragma unroll
            for (int r = 0; r < 4; ++r) {
                const int m = m0 + wm * 64 + mf * 16 + g * 4 + r;
                out[(size_t)m * D_MODEL + o] = acc[mf][nf][r] + bv_;
            }
        }
    }
}

// ---------------------------------------------------------------------------
extern "C" void kernel_launch(void* const* d_in, const int* in_sizes, int n_in,
                              void* d_out, int out_size, void* d_ws, size_t ws_size,
                              hipStream_t stream) {
    const float* Q  = (const float*)d_in[0];
    const float* K  = (const float*)d_in[1];
    const float* V  = (const float*)d_in[2];
    const float* Wq = (const float*)d_in[3];
    const float* bq = (const float*)d_in[4];
    const float* Wk = (const float*)d_in[5];
    const float* bk = (const float*)d_in[6];
    const float* Wv = (const float*)d_in[7];
    const float* bv = (const float*)d_in[8];
    const float* Wo = (const float*)d_in[9];
    const float* bo = (const float*)d_in[10];
    float* out = (float*)d_out;

    const size_t HEAD_ELEMS = (size_t)BATCH * NHEADS * S_LEN * DK;  // 4.19M
    unsigned short* qh = (unsigned short*)d_ws;
    unsigned short* kh = qh + HEAD_ELEMS;
    unsigned short* vh = kh + HEAD_ELEMS;
    unsigned short* ah = vh + HEAD_ELEMS;
    float* mtab = (float*)(ah + HEAD_ELEMS);

    mask_kernel<<<dim3(S_LEN / 256), 256, 0, stream>>>(mtab);
    proj_gemm<<<dim3(M_ROWS / 128, D_MODEL / 128, 3), 256, 0, stream>>>(
        Q, K, V, Wq, Wk, Wv, bq, bk, bv, qh, kh, vh);
    attn_kernel<<<dim3(S_LEN / 128, BATCH * NHEADS), 512, 0, stream>>>(
        qh, kh, vh, mtab, ah);
    out_gemm<<<dim3(M_ROWS / 128, D_MODEL / 128), 256, 0, stream>>>(
        ah, Wo, bo, out);
}

// Round 3
// 161.538 us; speedup vs baseline: 1.7651x; 1.2587x over previous
//
#include <hip/hip_runtime.h>
#include <hip/hip_bf16.h>

// ---------------------------------------------------------------------------
// EnhancedMultiHeadAttention on MI355X (gfx950)
// B=2, S=2048, D=1024, H=16, dk=64. fp32 in/out, bf16 MFMA compute.
// Round 3: pre-convert X/W to bf16 once; GEMMs rebuilt on m97 structure
// (128x128 tile, BK=64, global_load_lds width-16, 2-barrier K-loop).
// ---------------------------------------------------------------------------

#define S_LEN 2048
#define D_MODEL 1024
#define NHEADS 16
#define DK 64
#define BATCH 2
#define M_ROWS (BATCH * S_LEN)   // 4096
#define LOG2E 1.4426950408889634f

typedef float f32x4 __attribute__((ext_vector_type(4)));
typedef short s16x8 __attribute__((ext_vector_type(8)));
typedef unsigned short u16x4 __attribute__((ext_vector_type(4)));

__device__ __forceinline__ unsigned short f2bf(float f) {
    unsigned u = __builtin_bit_cast(unsigned, f);
    u = (u + 0x7FFFu + ((u >> 16) & 1u)) >> 16;
    return (unsigned short)u;
}

__device__ __forceinline__ float fast_exp2(float x) {
    float r;
    asm("v_exp_f32 %0, %1" : "=v"(r) : "v"(x));
    return r;
}

#define GLD16(gptr, lptr)                                                     \
    __builtin_amdgcn_global_load_lds(                                         \
        (const __attribute__((address_space(1))) void*)(gptr),                \
        (__attribute__((address_space(3))) void*)(lptr), 16, 0, 0)

// ---------------------------------------------------------------------------
// Mask table in exp2 domain: m[d] = log2e * 0.25 * sum_w exp(-d^2/(2 w^2))
// ---------------------------------------------------------------------------
__global__ void mask_kernel(float* __restrict__ mtab) {
    int d = blockIdx.x * 256 + threadIdx.x;
    if (d < S_LEN) {
        float d2 = (float)d * (float)d;
        mtab[d] = LOG2E * 0.25f * (__expf(-d2 * (1.0f / 50.0f)) +
                                   __expf(-d2 * (1.0f / 200.0f)) +
                                   __expf(-d2 * (1.0f / 800.0f)) +
                                   __expf(-d2 * (1.0f / 3200.0f)));
    }
}

// ---------------------------------------------------------------------------
// fp32 -> bf16 conversion of Q,K,V,Wq,Wk,Wv,Wo (each element exactly once)
// ---------------------------------------------------------------------------
__global__ __launch_bounds__(256) void convert_kernel(
    const float* __restrict__ Q, const float* __restrict__ K,
    const float* __restrict__ V,
    const float* __restrict__ Wq, const float* __restrict__ Wk,
    const float* __restrict__ Wv, const float* __restrict__ Wo,
    unsigned short* __restrict__ Qb, unsigned short* __restrict__ Kb,
    unsigned short* __restrict__ Vb,
    unsigned short* __restrict__ Wqb, unsigned short* __restrict__ Wkb,
    unsigned short* __restrict__ Wvb, unsigned short* __restrict__ Wob)
{
    const int XN = M_ROWS * D_MODEL / 8;    // 524288 chunks per X
    const int WN = D_MODEL * D_MODEL / 8;   // 131072 chunks per W
    int i = blockIdx.x * 256 + threadIdx.x;
    const float* src;
    unsigned short* dst;
    int off;
    if (i < 3 * XN) {
        if (i < XN)          { src = Q; dst = Qb; off = i; }
        else if (i < 2 * XN) { src = K; dst = Kb; off = i - XN; }
        else                 { src = V; dst = Vb; off = i - 2 * XN; }
    } else {
        int j = i - 3 * XN;
        if (j < WN)          { src = Wq; dst = Wqb; off = j; }
        else if (j < 2 * WN) { src = Wk; dst = Wkb; off = j - WN; }
        else if (j < 3 * WN) { src = Wv; dst = Wvb; off = j - 2 * WN; }
        else                 { src = Wo; dst = Wob; off = j - 3 * WN; }
    }
    f32x4 v0 = *(const f32x4*)(src + (size_t)off * 8);
    f32x4 v1 = *(const f32x4*)(src + (size_t)off * 8 + 4);
    s16x8 o;
#pragma unroll
    for (int j = 0; j < 4; ++j) {
        o[j]     = (short)f2bf(v0[j]);
        o[j + 4] = (short)f2bf(v1[j]);
    }
    *(s16x8*)(dst + (size_t)off * 8) = o;
}

// ---------------------------------------------------------------------------
// m97-structure GEMM core: C[128x128] = A[128xK] @ B[128xK]^T  (bf16 inputs)
// BK=64, 4 waves, global_load_lds width-16 staging, linear LDS.
// A row-major [M][K], B row-major [N][K] (i.e. W as stored: out-col rows).
// ---------------------------------------------------------------------------
__device__ __forceinline__ void gemm_core_128(
    const unsigned short* __restrict__ A, const unsigned short* __restrict__ B,
    unsigned short* As, unsigned short* Bs,
    int m0, int n0, int K, int tid, f32x4 acc[4][4])
{
    const int wid  = tid >> 6;
    const int lane = tid & 63;
    const int g    = lane >> 4;
    const int c    = lane & 15;
    const int wm   = wid >> 1;
    const int wn   = wid & 1;

    const int srow   = tid >> 3;   // 0..31 within a 32-row round
    const int schunk = tid & 7;    // 16B chunk within a 128B row

    for (int kt = 0; kt < K / 64; ++kt) {
        const int k0 = kt * 64;
        __syncthreads();   // previous compute done, LDS free
#pragma unroll
        for (int r = 0; r < 4; ++r) {
            const int row = r * 32 + srow;
            GLD16(A + (size_t)(m0 + row) * K + k0 + schunk * 8,
                  &As[(r * 256 + wid * 64) * 8]);
        }
#pragma unroll
        for (int r = 0; r < 4; ++r) {
            const int row = r * 32 + srow;
            GLD16(B + (size_t)(n0 + row) * K + k0 + schunk * 8,
                  &Bs[(r * 256 + wid * 64) * 8]);
        }
        __syncthreads();   // staging visible (drains vmcnt)

        s16x8 a[2][4];
#pragma unroll
        for (int ks = 0; ks < 2; ++ks)
#pragma unroll
            for (int mf = 0; mf < 4; ++mf)
                a[ks][mf] = *(const s16x8*)
                    &As[(wm * 64 + mf * 16 + c) * 64 + ks * 32 + g * 8];
#pragma unroll
        for (int ks = 0; ks < 2; ++ks) {
#pragma unroll
            for (int nf = 0; nf < 4; ++nf) {
                s16x8 b = *(const s16x8*)
                    &Bs[(wn * 64 + nf * 16 + c) * 64 + ks * 32 + g * 8];
#pragma unroll
                for (int mf = 0; mf < 4; ++mf)
                    acc[mf][nf] = __builtin_amdgcn_mfma_f32_16x16x32_bf16(
                        a[ks][mf], b, acc[mf][nf], 0, 0, 0);
            }
        }
    }
}

// ---------------------------------------------------------------------------
// QKV projection: Y = X @ W^T + b -> bf16 head layout [B][H][S][dk];
// q gets *(0.125*log2e) fold.
// ---------------------------------------------------------------------------
__global__ __launch_bounds__(256) void proj_gemm(
    const unsigned short* __restrict__ Qx, const unsigned short* __restrict__ Kx,
    const unsigned short* __restrict__ Vx,
    const unsigned short* __restrict__ Wq, const unsigned short* __restrict__ Wk,
    const unsigned short* __restrict__ Wv,
    const float* __restrict__ bq, const float* __restrict__ bk,
    const float* __restrict__ bv,
    unsigned short* __restrict__ qo, unsigned short* __restrict__ ko,
    unsigned short* __restrict__ vo)
{
    const int z = blockIdx.z;
    const unsigned short* X = (z == 0) ? Qx : (z == 1) ? Kx : Vx;
    const unsigned short* W = (z == 0) ? Wq : (z == 1) ? Wk : Wv;
    const float* bias       = (z == 0) ? bq : (z == 1) ? bk : bv;
    unsigned short* out     = (z == 0) ? qo : (z == 1) ? ko : vo;
    const float scale = (z == 0) ? (0.125f * LOG2E) : 1.0f;

    __shared__ unsigned short As[128 * 64];
    __shared__ unsigned short Bs[128 * 64];

    const int tid = threadIdx.x;
    const int m0  = blockIdx.x * 128;
    const int n0  = blockIdx.y * 128;

    f32x4 acc[4][4];
#pragma unroll
    for (int i = 0; i < 4; ++i)
#pragma unroll
        for (int j = 0; j < 4; ++j) acc[i][j] = (f32x4){0.f, 0.f, 0.f, 0.f};

    gemm_core_128(X, W, As, Bs, m0, n0, D_MODEL, tid, acc);

    const int lane = tid & 63;
    const int g    = lane >> 4;
    const int c    = lane & 15;
    const int wm   = (tid >> 6) >> 1;
    const int wn   = (tid >> 6) & 1;

#pragma unroll
    for (int mf = 0; mf < 4; ++mf) {
#pragma unroll
        for (int nf = 0; nf < 4; ++nf) {
            const int o = n0 + wn * 64 + nf * 16 + c;
            const float bv_ = bias[o];
            const int h  = o >> 6;
            const int dd = o & 63;
#pragma unroll
            for (int r = 0; r < 4; ++r) {
                const int m = m0 + wm * 64 + mf * 16 + g * 4 + r;
                const int b = m >> 11;
                const int s = m & (S_LEN - 1);
                const float val = (acc[mf][nf][r] + bv_) * scale;
                out[(((size_t)(b * NHEADS + h)) * S_LEN + s) * DK + dd] = f2bf(val);
            }
        }
    }
}

// ---------------------------------------------------------------------------
// Output projection: Y = A @ Wo^T + bo  (fp32 out)
// ---------------------------------------------------------------------------
__global__ __launch_bounds__(256) void out_gemm(
    const unsigned short* __restrict__ A,
    const unsigned short* __restrict__ W,
    const float* __restrict__ bias,
    float* __restrict__ out)
{
    __shared__ unsigned short As[128 * 64];
    __shared__ unsigned short Bs[128 * 64];

    const int tid = threadIdx.x;
    const int m0  = blockIdx.x * 128;
    const int n0  = blockIdx.y * 128;

    f32x4 acc[4][4];
#pragma unroll
    for (int i = 0; i < 4; ++i)
#pragma unroll
        for (int j = 0; j < 4; ++j) acc[i][j] = (f32x4){0.f, 0.f, 0.f, 0.f};

    gemm_core_128(A, W, As, Bs, m0, n0, D_MODEL, tid, acc);

    const int lane = tid & 63;
    const int g    = lane >> 4;
    const int c    = lane & 15;
    const int wm   = (tid >> 6) >> 1;
    const int wn   = (tid >> 6) & 1;

#pragma unroll
    for (int mf = 0; mf < 4; ++mf) {
#pragma unroll
        for (int nf = 0; nf < 4; ++nf) {
            const int o = n0 + wn * 64 + nf * 16 + c;
            const float bv_ = bias[o];
#pragma unroll
            for (int r = 0; r < 4; ++r) {
                const int m = m0 + wm * 64 + mf * 16 + g * 4 + r;
                out[(size_t)m * D_MODEL + o] = acc[mf][nf][r] + bv_;
            }
        }
    }
}

// ---------------------------------------------------------------------------
// Flash attention, swapped-QK^T structure (unchanged from round 2).
// grid (S/128, B*H), 8 waves/block, 16 q-rows/wave, KBLK=64.
// ---------------------------------------------------------------------------
__global__ __launch_bounds__(512) void attn_kernel(
    const unsigned short* __restrict__ qh,
    const unsigned short* __restrict__ kh,
    const unsigned short* __restrict__ vh,
    const float* __restrict__ mask_tab,
    unsigned short* __restrict__ attn_out)
{
    __shared__ float mtab[S_LEN];
    __shared__ unsigned short Kt[64 * 64];
    __shared__ unsigned short Vt[64 * 64];
    __shared__ unsigned short Pt[8][16 * 64];

    const int tid  = threadIdx.x;
    const int wid  = tid >> 6;
    const int lane = tid & 63;
    const int g    = lane >> 4;
    const int c    = lane & 15;
    const int bh   = blockIdx.y;
    const int b    = bh >> 4;
    const int h    = bh & 15;
    const int q0w  = blockIdx.x * 128 + wid * 16;

    *(f32x4*)&mtab[tid * 4] = *(const f32x4*)&mask_tab[tid * 4];

    const size_t head_off = (size_t)bh * S_LEN * DK;
    const unsigned short* qp = qh + head_off;
    const unsigned short* kp = kh + head_off;
    const unsigned short* vp = vh + head_off;

    s16x8 aq[2];
    {
        const unsigned short* qrow = qp + (size_t)(q0w + c) * DK;
        aq[0] = *(const s16x8*)(qrow + g * 8);
        aq[1] = *(const s16x8*)(qrow + 32 + g * 8);
    }

    f32x4 acc_o[4];
#pragma unroll
    for (int nf = 0; nf < 4; ++nf) acc_o[nf] = (f32x4){0.f, 0.f, 0.f, 0.f};
    float m_l = -1e30f, l_l = 0.f;

    const int srowK = tid >> 3;
    const int soffE = (tid & 7) * 8;
    const int vd0   = (tid & 31) * 2;
    const int vkq   = (tid >> 5) * 4;

    s16x8 kreg;
    unsigned vreg[4];
    kreg = *(const s16x8*)&kp[(size_t)srowK * DK + soffE];
#pragma unroll
    for (int i = 0; i < 4; ++i)
        vreg[i] = *(const unsigned*)&vp[(size_t)(vkq + i) * DK + vd0];

    unsigned short* Ptw = Pt[wid];

    for (int kt = 0; kt < S_LEN / 64; ++kt) {
        const int k0 = kt * 64;
        __syncthreads();

        *(s16x8*)((char*)Kt + srowK * 128 + ((soffE * 2) ^ ((srowK & 7) << 4))) = kreg;
        {
            u16x4 lo4, hi4;
#pragma unroll
            for (int i = 0; i < 4; ++i) {
                lo4[i] = (unsigned short)vreg[i];
                hi4[i] = (unsigned short)(vreg[i] >> 16);
            }
            *(u16x4*)((char*)Vt + vd0 * 128 + ((vkq * 2) ^ ((vd0 & 7) << 4))) = lo4;
            *(u16x4*)((char*)Vt + (vd0 + 1) * 128 +
                      ((vkq * 2) ^ (((vd0 + 1) & 7) << 4))) = hi4;
        }
        if (kt < S_LEN / 64 - 1) {
            const int k1 = k0 + 64;
            kreg = *(const s16x8*)&kp[(size_t)(k1 + srowK) * DK + soffE];
#pragma unroll
            for (int i = 0; i < 4; ++i)
                vreg[i] = *(const unsigned*)&vp[(size_t)(k1 + vkq + i) * DK + vd0];
        }
        __syncthreads();

        f32x4 st[4];
#pragma unroll
        for (int nf = 0; nf < 4; ++nf) {
            st[nf] = (f32x4){0.f, 0.f, 0.f, 0.f};
#pragma unroll
            for (int f = 0; f < 2; ++f) {
                const int row = nf * 16 + c;
                s16x8 kf = *(const s16x8*)((const char*)Kt + row * 128 +
                                           ((f * 64 + g * 16) ^ ((row & 7) << 4)));
                st[nf] = __builtin_amdgcn_mfma_f32_16x16x32_bf16(
                    kf, aq[f], st[nf], 0, 0, 0);
            }
        }

        const int diff = q0w - k0;
        if (diff >= -15 && diff <= 510) {
            const int dbase = q0w + c - k0;
#pragma unroll
            for (int nf = 0; nf < 4; ++nf) {
#pragma unroll
                for (int r = 0; r < 4; ++r) {
                    const int d = dbase - (nf * 16 + g * 4 + r);
                    if (d >= 0) st[nf][r] += mtab[d];
                }
            }
        }

        float tm = -1e30f;
#pragma unroll
        for (int nf = 0; nf < 4; ++nf)
#pragma unroll
            for (int r = 0; r < 4; ++r) tm = fmaxf(tm, st[nf][r]);
        tm = fmaxf(tm, __shfl_xor(tm, 16));
        tm = fmaxf(tm, __shfl_xor(tm, 32));

        const float mnew = fmaxf(m_l, tm);
        const float csc  = fast_exp2(m_l - mnew);
        m_l = mnew;

        float ps = 0.f;
#pragma unroll
        for (int nf = 0; nf < 4; ++nf)
#pragma unroll
            for (int r = 0; r < 4; ++r) {
                const float p = fast_exp2(st[nf][r] - mnew);
                st[nf][r] = p;
                ps += p;
            }
        ps += __shfl_xor(ps, 16);
        ps += __shfl_xor(ps, 32);
        l_l = l_l * csc + ps;

        float cscq[4];
#pragma unroll
        for (int r = 0; r < 4; ++r) cscq[r] = __shfl(csc, g * 4 + r);
#pragma unroll
        for (int nf = 0; nf < 4; ++nf)
#pragma unroll
            for (int r = 0; r < 4; ++r) acc_o[nf][r] *= cscq[r];

#pragma unroll
        for (int nf = 0; nf < 4; ++nf) {
            u16x4 pk;
#pragma unroll
            for (int r = 0; r < 4; ++r) pk[r] = f2bf(st[nf][r]);
            *(u16x4*)((char*)Ptw + c * 128 +
                      ((nf * 32 + g * 8) ^ ((c & 7) << 4))) = pk;
        }

#pragma unroll
        for (int f = 0; f < 2; ++f) {
            s16x8 pa = *(const s16x8*)((const char*)Ptw + c * 128 +
                                       ((f * 64 + g * 16) ^ ((c & 7) << 4)));
#pragma unroll
            for (int nf = 0; nf < 4; ++nf) {
                const int row = nf * 16 + c;
                s16x8 vb = *(const s16x8*)((const char*)Vt + row * 128 +
                                           ((f * 64 + g * 16) ^ ((row & 7) << 4)));
                acc_o[nf] = __builtin_amdgcn_mfma_f32_16x16x32_bf16(
                    pa, vb, acc_o[nf], 0, 0, 0);
            }
        }
    }

    float lq[4];
#pragma unroll
    for (int r = 0; r < 4; ++r) lq[r] = __shfl(l_l, g * 4 + r);
#pragma unroll
    for (int nf = 0; nf < 4; ++nf) {
#pragma unroll
        for (int r = 0; r < 4; ++r) {
            const int i_glob = q0w + g * 4 + r;
            const int d = nf * 16 + c;
            const float o = acc_o[nf][r] / lq[r];
            attn_out[((size_t)(b * S_LEN + i_glob)) * D_MODEL + h * DK + d] = f2bf(o);
        }
    }
}

// ---------------------------------------------------------------------------
extern "C" void kernel_launch(void* const* d_in, const int* in_sizes, int n_in,
                              void* d_out, int out_size, void* d_ws, size_t ws_size,
                              hipStream_t stream) {
    const float* Q  = (const float*)d_in[0];
    const float* K  = (const float*)d_in[1];
    const float* V  = (const float*)d_in[2];
    const float* Wq = (const float*)d_in[3];
    const float* bq = (const float*)d_in[4];
    const float* Wk = (const float*)d_in[5];
    const float* bk = (const float*)d_in[6];
    const float* Wv = (const float*)d_in[7];
    const float* bv = (const float*)d_in[8];
    const float* Wo = (const float*)d_in[9];
    const float* bo = (const float*)d_in[10];
    float* out = (float*)d_out;

    // ws carve-up
    const size_t XE = (size_t)M_ROWS * D_MODEL;        // 4.19M elems
    const size_t WE = (size_t)D_MODEL * D_MODEL;       // 1.05M elems
    unsigned short* qh  = (unsigned short*)d_ws;       // head-layout q
    unsigned short* kh  = qh + XE;
    unsigned short* vh  = kh + XE;
    unsigned short* ah  = vh + XE;                     // attention out
    unsigned short* Qb  = ah + XE;                     // bf16 inputs
    unsigned short* Kb  = Qb + XE;
    unsigned short* Vb  = Kb + XE;
    unsigned short* Wqb = Vb + XE;
    unsigned short* Wkb = Wqb + WE;
    unsigned short* Wvb = Wkb + WE;
    unsigned short* Wob = Wvb + WE;
    float* mtab = (float*)(Wob + WE);

    mask_kernel<<<dim3(S_LEN / 256), 256, 0, stream>>>(mtab);
    convert_kernel<<<dim3((3 * XE / 8 + 4 * WE / 8) / 256), 256, 0, stream>>>(
        Q, K, V, Wq, Wk, Wv, Wo, Qb, Kb, Vb, Wqb, Wkb, Wvb, Wob);
    proj_gemm<<<dim3(M_ROWS / 128, D_MODEL / 128, 3), 256, 0, stream>>>(
        Qb, Kb, Vb, Wqb, Wkb, Wvb, bq, bk, bv, qh, kh, vh);
    attn_kernel<<<dim3(S_LEN / 128, BATCH * NHEADS), 512, 0, stream>>>(
        qh, kh, vh, mtab, ah);
    out_gemm<<<dim3(M_ROWS / 128, D_MODEL / 128), 256, 0, stream>>>(
        ah, Wob, bo, out);
}

// Round 4
// 152.992 us; speedup vs baseline: 1.8638x; 1.0559x over previous
//
#include <hip/hip_runtime.h>
#include <hip/hip_bf16.h>

// ---------------------------------------------------------------------------
// EnhancedMultiHeadAttention on MI355X (gfx950)
// B=2, S=2048, D=1024, H=16, dk=64. fp32 in/out, bf16 MFMA compute.
// Round 4: attention VALU diet — cvt_pk_bf16 P-pack (T12 primitive),
// defer-max THR=8 (T13), v_max3 (T17), Vt write-swizzle fix, setprio (T5).
// ---------------------------------------------------------------------------

#define S_LEN 2048
#define D_MODEL 1024
#define NHEADS 16
#define DK 64
#define BATCH 2
#define M_ROWS (BATCH * S_LEN)   // 4096
#define LOG2E 1.4426950408889634f

typedef float f32x4 __attribute__((ext_vector_type(4)));
typedef short s16x8 __attribute__((ext_vector_type(8)));
typedef unsigned short u16x4 __attribute__((ext_vector_type(4)));
typedef unsigned u32x2 __attribute__((ext_vector_type(2)));

__device__ __forceinline__ unsigned short f2bf(float f) {
    unsigned u = __builtin_bit_cast(unsigned, f);
    u = (u + 0x7FFFu + ((u >> 16) & 1u)) >> 16;
    return (unsigned short)u;
}

__device__ __forceinline__ float fast_exp2(float x) {
    float r;
    asm("v_exp_f32 %0, %1" : "=v"(r) : "v"(x));
    return r;
}

__device__ __forceinline__ unsigned cvt_pk_bf16(float a, float b) {
    unsigned r;
    asm("v_cvt_pk_bf16_f32 %0, %1, %2" : "=v"(r) : "v"(a), "v"(b));
    return r;
}

__device__ __forceinline__ float max3f(float a, float b, float c) {
    float r;
    asm("v_max3_f32 %0, %1, %2, %3" : "=v"(r) : "v"(a), "v"(b), "v"(c));
    return r;
}

#define GLD16(gptr, lptr)                                                     \
    __builtin_amdgcn_global_load_lds(                                         \
        (const __attribute__((address_space(1))) void*)(gptr),                \
        (__attribute__((address_space(3))) void*)(lptr), 16, 0, 0)

// ---------------------------------------------------------------------------
// Mask table in exp2 domain: m[d] = log2e * 0.25 * sum_w exp(-d^2/(2 w^2))
// ---------------------------------------------------------------------------
__global__ void mask_kernel(float* __restrict__ mtab) {
    int d = blockIdx.x * 256 + threadIdx.x;
    if (d < S_LEN) {
        float d2 = (float)d * (float)d;
        mtab[d] = LOG2E * 0.25f * (__expf(-d2 * (1.0f / 50.0f)) +
                                   __expf(-d2 * (1.0f / 200.0f)) +
                                   __expf(-d2 * (1.0f / 800.0f)) +
                                   __expf(-d2 * (1.0f / 3200.0f)));
    }
}

// ---------------------------------------------------------------------------
// fp32 -> bf16 conversion of Q,K,V,Wq,Wk,Wv,Wo (each element exactly once)
// ---------------------------------------------------------------------------
__global__ __launch_bounds__(256) void convert_kernel(
    const float* __restrict__ Q, const float* __restrict__ K,
    const float* __restrict__ V,
    const float* __restrict__ Wq, const float* __restrict__ Wk,
    const float* __restrict__ Wv, const float* __restrict__ Wo,
    unsigned short* __restrict__ Qb, unsigned short* __restrict__ Kb,
    unsigned short* __restrict__ Vb,
    unsigned short* __restrict__ Wqb, unsigned short* __restrict__ Wkb,
    unsigned short* __restrict__ Wvb, unsigned short* __restrict__ Wob)
{
    const int XN = M_ROWS * D_MODEL / 8;
    const int WN = D_MODEL * D_MODEL / 8;
    int i = blockIdx.x * 256 + threadIdx.x;
    const float* src;
    unsigned short* dst;
    int off;
    if (i < 3 * XN) {
        if (i < XN)          { src = Q; dst = Qb; off = i; }
        else if (i < 2 * XN) { src = K; dst = Kb; off = i - XN; }
        else                 { src = V; dst = Vb; off = i - 2 * XN; }
    } else {
        int j = i - 3 * XN;
        if (j < WN)          { src = Wq; dst = Wqb; off = j; }
        else if (j < 2 * WN) { src = Wk; dst = Wkb; off = j - WN; }
        else if (j < 3 * WN) { src = Wv; dst = Wvb; off = j - 2 * WN; }
        else                 { src = Wo; dst = Wob; off = j - 3 * WN; }
    }
    f32x4 v0 = *(const f32x4*)(src + (size_t)off * 8);
    f32x4 v1 = *(const f32x4*)(src + (size_t)off * 8 + 4);
    s16x8 o;
#pragma unroll
    for (int j = 0; j < 4; ++j) {
        o[j]     = (short)f2bf(v0[j]);
        o[j + 4] = (short)f2bf(v1[j]);
    }
    *(s16x8*)(dst + (size_t)off * 8) = o;
}

// ---------------------------------------------------------------------------
// m97-structure GEMM core: C[128x128] = A[128xK] @ B[128xK]^T  (bf16 inputs)
// ---------------------------------------------------------------------------
__device__ __forceinline__ void gemm_core_128(
    const unsigned short* __restrict__ A, const unsigned short* __restrict__ B,
    unsigned short* As, unsigned short* Bs,
    int m0, int n0, int K, int tid, f32x4 acc[4][4])
{
    const int wid  = tid >> 6;
    const int lane = tid & 63;
    const int g    = lane >> 4;
    const int c    = lane & 15;
    const int wm   = wid >> 1;
    const int wn   = wid & 1;

    const int srow   = tid >> 3;
    const int schunk = tid & 7;

    for (int kt = 0; kt < K / 64; ++kt) {
        const int k0 = kt * 64;
        __syncthreads();
#pragma unroll
        for (int r = 0; r < 4; ++r) {
            const int row = r * 32 + srow;
            GLD16(A + (size_t)(m0 + row) * K + k0 + schunk * 8,
                  &As[(r * 256 + wid * 64) * 8]);
        }
#pragma unroll
        for (int r = 0; r < 4; ++r) {
            const int row = r * 32 + srow;
            GLD16(B + (size_t)(n0 + row) * K + k0 + schunk * 8,
                  &Bs[(r * 256 + wid * 64) * 8]);
        }
        __syncthreads();

        s16x8 a[2][4];
#pragma unroll
        for (int ks = 0; ks < 2; ++ks)
#pragma unroll
            for (int mf = 0; mf < 4; ++mf)
                a[ks][mf] = *(const s16x8*)
                    &As[(wm * 64 + mf * 16 + c) * 64 + ks * 32 + g * 8];
#pragma unroll
        for (int ks = 0; ks < 2; ++ks) {
#pragma unroll
            for (int nf = 0; nf < 4; ++nf) {
                s16x8 b = *(const s16x8*)
                    &Bs[(wn * 64 + nf * 16 + c) * 64 + ks * 32 + g * 8];
#pragma unroll
                for (int mf = 0; mf < 4; ++mf)
                    acc[mf][nf] = __builtin_amdgcn_mfma_f32_16x16x32_bf16(
                        a[ks][mf], b, acc[mf][nf], 0, 0, 0);
            }
        }
    }
}

// ---------------------------------------------------------------------------
// QKV projection: Y = X @ W^T + b -> bf16 head layout [B][H][S][dk]
// ---------------------------------------------------------------------------
__global__ __launch_bounds__(256) void proj_gemm(
    const unsigned short* __restrict__ Qx, const unsigned short* __restrict__ Kx,
    const unsigned short* __restrict__ Vx,
    const unsigned short* __restrict__ Wq, const unsigned short* __restrict__ Wk,
    const unsigned short* __restrict__ Wv,
    const float* __restrict__ bq, const float* __restrict__ bk,
    const float* __restrict__ bv,
    unsigned short* __restrict__ qo, unsigned short* __restrict__ ko,
    unsigned short* __restrict__ vo)
{
    const int z = blockIdx.z;
    const unsigned short* X = (z == 0) ? Qx : (z == 1) ? Kx : Vx;
    const unsigned short* W = (z == 0) ? Wq : (z == 1) ? Wk : Wv;
    const float* bias       = (z == 0) ? bq : (z == 1) ? bk : bv;
    unsigned short* out     = (z == 0) ? qo : (z == 1) ? ko : vo;
    const float scale = (z == 0) ? (0.125f * LOG2E) : 1.0f;

    __shared__ unsigned short As[128 * 64];
    __shared__ unsigned short Bs[128 * 64];

    const int tid = threadIdx.x;
    const int m0  = blockIdx.x * 128;
    const int n0  = blockIdx.y * 128;

    f32x4 acc[4][4];
#pragma unroll
    for (int i = 0; i < 4; ++i)
#pragma unroll
        for (int j = 0; j < 4; ++j) acc[i][j] = (f32x4){0.f, 0.f, 0.f, 0.f};

    gemm_core_128(X, W, As, Bs, m0, n0, D_MODEL, tid, acc);

    const int lane = tid & 63;
    const int g    = lane >> 4;
    const int c    = lane & 15;
    const int wm   = (tid >> 6) >> 1;
    const int wn   = (tid >> 6) & 1;

#pragma unroll
    for (int mf = 0; mf < 4; ++mf) {
#pragma unroll
        for (int nf = 0; nf < 4; ++nf) {
            const int o = n0 + wn * 64 + nf * 16 + c;
            const float bv_ = bias[o];
            const int h  = o >> 6;
            const int dd = o & 63;
#pragma unroll
            for (int r = 0; r < 4; ++r) {
                const int m = m0 + wm * 64 + mf * 16 + g * 4 + r;
                const int b = m >> 11;
                const int s = m & (S_LEN - 1);
                const float val = (acc[mf][nf][r] + bv_) * scale;
                out[(((size_t)(b * NHEADS + h)) * S_LEN + s) * DK + dd] = f2bf(val);
            }
        }
    }
}

// ---------------------------------------------------------------------------
// Output projection: Y = A @ Wo^T + bo  (fp32 out)
// ---------------------------------------------------------------------------
__global__ __launch_bounds__(256) void out_gemm(
    const unsigned short* __restrict__ A,
    const unsigned short* __restrict__ W,
    const float* __restrict__ bias,
    float* __restrict__ out)
{
    __shared__ unsigned short As[128 * 64];
    __shared__ unsigned short Bs[128 * 64];

    const int tid = threadIdx.x;
    const int m0  = blockIdx.x * 128;
    const int n0  = blockIdx.y * 128;

    f32x4 acc[4][4];
#pragma unroll
    for (int i = 0; i < 4; ++i)
#pragma unroll
        for (int j = 0; j < 4; ++j) acc[i][j] = (f32x4){0.f, 0.f, 0.f, 0.f};

    gemm_core_128(A, W, As, Bs, m0, n0, D_MODEL, tid, acc);

    const int lane = tid & 63;
    const int g    = lane >> 4;
    const int c    = lane & 15;
    const int wm   = (tid >> 6) >> 1;
    const int wn   = (tid >> 6) & 1;

#pragma unroll
    for (int mf = 0; mf < 4; ++mf) {
#pragma unroll
        for (int nf = 0; nf < 4; ++nf) {
            const int o = n0 + wn * 64 + nf * 16 + c;
            const float bv_ = bias[o];
#pragma unroll
            for (int r = 0; r < 4; ++r) {
                const int m = m0 + wm * 64 + mf * 16 + g * 4 + r;
                out[(size_t)m * D_MODEL + o] = acc[mf][nf][r] + bv_;
            }
        }
    }
}

// ---------------------------------------------------------------------------
// Flash attention, swapped-QK^T structure + R4 VALU diet.
// grid (S/128, B*H), 8 waves/block, 16 q-rows/wave, KBLK=64.
// ---------------------------------------------------------------------------
#define VSWZ(row) ((((row) >> 1) & 7) << 4)

__global__ __launch_bounds__(512) void attn_kernel(
    const unsigned short* __restrict__ qh,
    const unsigned short* __restrict__ kh,
    const unsigned short* __restrict__ vh,
    const float* __restrict__ mask_tab,
    unsigned short* __restrict__ attn_out)
{
    __shared__ float mtab[S_LEN];
    __shared__ unsigned short Kt[64 * 64];
    __shared__ unsigned short Vt[64 * 64];
    __shared__ unsigned short Pt[8][16 * 64];

    const int tid  = threadIdx.x;
    const int wid  = tid >> 6;
    const int lane = tid & 63;
    const int g    = lane >> 4;
    const int c    = lane & 15;
    const int bh   = blockIdx.y;
    const int b    = bh >> 4;
    const int h    = bh & 15;
    const int q0w  = blockIdx.x * 128 + wid * 16;

    *(f32x4*)&mtab[tid * 4] = *(const f32x4*)&mask_tab[tid * 4];

    const size_t head_off = (size_t)bh * S_LEN * DK;
    const unsigned short* qp = qh + head_off;
    const unsigned short* kp = kh + head_off;
    const unsigned short* vp = vh + head_off;

    s16x8 aq[2];
    {
        const unsigned short* qrow = qp + (size_t)(q0w + c) * DK;
        aq[0] = *(const s16x8*)(qrow + g * 8);
        aq[1] = *(const s16x8*)(qrow + 32 + g * 8);
    }

    f32x4 acc_o[4];
#pragma unroll
    for (int nf = 0; nf < 4; ++nf) acc_o[nf] = (f32x4){0.f, 0.f, 0.f, 0.f};
    float m_l = -1e30f, l_l = 0.f;

    const int srowK = tid >> 3;
    const int soffE = (tid & 7) * 8;
    const int vd0   = (tid & 31) * 2;
    const int vkq   = (tid >> 5) * 4;

    s16x8 kreg;
    unsigned vreg[4];
    kreg = *(const s16x8*)&kp[(size_t)srowK * DK + soffE];
#pragma unroll
    for (int i = 0; i < 4; ++i)
        vreg[i] = *(const unsigned*)&vp[(size_t)(vkq + i) * DK + vd0];

    unsigned short* Ptw = Pt[wid];

    for (int kt = 0; kt < S_LEN / 64; ++kt) {
        const int k0 = kt * 64;
        __syncthreads();

        // ---- staged registers -> LDS ----
        *(s16x8*)((char*)Kt + srowK * 128 + ((soffE * 2) ^ ((srowK & 7) << 4))) = kreg;
        {
            u16x4 lo4, hi4;
#pragma unroll
            for (int i = 0; i < 4; ++i) {
                lo4[i] = (unsigned short)vreg[i];
                hi4[i] = (unsigned short)(vreg[i] >> 16);
            }
            *(u16x4*)((char*)Vt + vd0 * 128 + ((vkq * 2) ^ VSWZ(vd0))) = lo4;
            *(u16x4*)((char*)Vt + (vd0 + 1) * 128 +
                      ((vkq * 2) ^ VSWZ(vd0 + 1))) = hi4;
        }
        // ---- prefetch next tile ----
        if (kt < S_LEN / 64 - 1) {
            const int k1 = k0 + 64;
            kreg = *(const s16x8*)&kp[(size_t)(k1 + srowK) * DK + soffE];
#pragma unroll
            for (int i = 0; i < 4; ++i)
                vreg[i] = *(const unsigned*)&vp[(size_t)(k1 + vkq + i) * DK + vd0];
        }
        __syncthreads();

        // ---- QK^T (swapped): lane holds q=c, k = nf*16+g*4+r ----
        f32x4 st[4];
        __builtin_amdgcn_s_setprio(1);
#pragma unroll
        for (int nf = 0; nf < 4; ++nf) {
            st[nf] = (f32x4){0.f, 0.f, 0.f, 0.f};
#pragma unroll
            for (int f = 0; f < 2; ++f) {
                const int row = nf * 16 + c;
                s16x8 kf = *(const s16x8*)((const char*)Kt + row * 128 +
                                           ((f * 64 + g * 16) ^ ((row & 7) << 4)));
                st[nf] = __builtin_amdgcn_mfma_f32_16x16x32_bf16(
                    kf, aq[f], st[nf], 0, 0, 0);
            }
        }
        __builtin_amdgcn_s_setprio(0);

        // ---- mask add (near-diagonal tiles only) ----
        const int diff = q0w - k0;
        if (diff >= -15 && diff <= 510) {
            const int dbase = q0w + c - k0;
#pragma unroll
            for (int nf = 0; nf < 4; ++nf) {
#pragma unroll
                for (int r = 0; r < 4; ++r) {
                    const int d = dbase - (nf * 16 + g * 4 + r);
                    if (d >= 0) st[nf][r] += mtab[d];
                }
            }
        }

        // ---- tile max via v_max3 ----
        float tm = st[0][0];
        tm = max3f(tm, st[0][1], st[0][2]);
        tm = max3f(tm, st[0][3], st[1][0]);
        tm = max3f(tm, st[1][1], st[1][2]);
        tm = max3f(tm, st[1][3], st[2][0]);
        tm = max3f(tm, st[2][1], st[2][2]);
        tm = max3f(tm, st[2][3], st[3][0]);
        tm = max3f(tm, st[3][1], st[3][2]);
        tm = fmaxf(tm, st[3][3]);
        tm = fmaxf(tm, __shfl_xor(tm, 16));
        tm = fmaxf(tm, __shfl_xor(tm, 32));

        // ---- defer-max (T13): rescale only when max grew past THR=8 ----
        if (__any(tm > m_l + 8.0f)) {
            const float mnew = fmaxf(m_l, tm);
            const float csc  = fast_exp2(m_l - mnew);
            m_l = mnew;
            l_l *= csc;
            f32x4 cscv;
#pragma unroll
            for (int r = 0; r < 4; ++r) cscv[r] = __shfl(csc, g * 4 + r);
#pragma unroll
            for (int nf = 0; nf < 4; ++nf) acc_o[nf] *= cscv;
        }

        // ---- P = exp2(st - m), row-sum ----
#pragma unroll
        for (int nf = 0; nf < 4; ++nf)
#pragma unroll
            for (int r = 0; r < 4; ++r)
                st[nf][r] = fast_exp2(st[nf][r] - m_l);
        {
            f32x4 s4 = (st[0] + st[1]) + (st[2] + st[3]);
            float ps = (s4[0] + s4[1]) + (s4[2] + s4[3]);
            ps += __shfl_xor(ps, 16);
            ps += __shfl_xor(ps, 32);
            l_l += ps;
        }

        // ---- P store: 2x cvt_pk -> one b64 per nf ----
#pragma unroll
        for (int nf = 0; nf < 4; ++nf) {
            u32x2 pk;
            pk[0] = cvt_pk_bf16(st[nf][0], st[nf][1]);
            pk[1] = cvt_pk_bf16(st[nf][2], st[nf][3]);
            *(u32x2*)((char*)Ptw + c * 128 +
                      ((nf * 32 + g * 8) ^ ((c & 7) << 4))) = pk;
        }

        // ---- PV: O[q][d] += P @ V ----
        __builtin_amdgcn_s_setprio(1);
#pragma unroll
        for (int f = 0; f < 2; ++f) {
            s16x8 pa = *(const s16x8*)((const char*)Ptw + c * 128 +
                                       ((f * 64 + g * 16) ^ ((c & 7) << 4)));
#pragma unroll
            for (int nf = 0; nf < 4; ++nf) {
                const int row = nf * 16 + c;
                s16x8 vb = *(const s16x8*)((const char*)Vt + row * 128 +
                                           ((f * 64 + g * 16) ^ VSWZ(row)));
                acc_o[nf] = __builtin_amdgcn_mfma_f32_16x16x32_bf16(
                    pa, vb, acc_o[nf], 0, 0, 0);
            }
        }
        __builtin_amdgcn_s_setprio(0);
    }

    // epilogue: normalize, store bf16
    float lq[4];
#pragma unroll
    for (int r = 0; r < 4; ++r) lq[r] = __shfl(l_l, g * 4 + r);
#pragma unroll
    for (int nf = 0; nf < 4; ++nf) {
#pragma unroll
        for (int r = 0; r < 4; ++r) {
            const int i_glob = q0w + g * 4 + r;
            const int d = nf * 16 + c;
            const float o = acc_o[nf][r] / lq[r];
            attn_out[((size_t)(b * S_LEN + i_glob)) * D_MODEL + h * DK + d] = f2bf(o);
        }
    }
}

// ---------------------------------------------------------------------------
extern "C" void kernel_launch(void* const* d_in, const int* in_sizes, int n_in,
                              void* d_out, int out_size, void* d_ws, size_t ws_size,
                              hipStream_t stream) {
    const float* Q  = (const float*)d_in[0];
    const float* K  = (const float*)d_in[1];
    const float* V  = (const float*)d_in[2];
    const float* Wq = (const float*)d_in[3];
    const float* bq = (const float*)d_in[4];
    const float* Wk = (const float*)d_in[5];
    const float* bk = (const float*)d_in[6];
    const float* Wv = (const float*)d_in[7];
    const float* bv = (const float*)d_in[8];
    const float* Wo = (const float*)d_in[9];
    const float* bo = (const float*)d_in[10];
    float* out = (float*)d_out;

    const size_t XE = (size_t)M_ROWS * D_MODEL;
    const size_t WE = (size_t)D_MODEL * D_MODEL;
    unsigned short* qh  = (unsigned short*)d_ws;
    unsigned short* kh  = qh + XE;
    unsigned short* vh  = kh + XE;
    unsigned short* ah  = vh + XE;
    unsigned short* Qb  = ah + XE;
    unsigned short* Kb  = Qb + XE;
    unsigned short* Vb  = Kb + XE;
    unsigned short* Wqb = Vb + XE;
    unsigned short* Wkb = Wqb + WE;
    unsigned short* Wvb = Wkb + WE;
    unsigned short* Wob = Wvb + WE;
    float* mtab = (float*)(Wob + WE);

    mask_kernel<<<dim3(S_LEN / 256), 256, 0, stream>>>(mtab);
    convert_kernel<<<dim3((3 * XE / 8 + 4 * WE / 8) / 256), 256, 0, stream>>>(
        Q, K, V, Wq, Wk, Wv, Wo, Qb, Kb, Vb, Wqb, Wkb, Wvb, Wob);
    proj_gemm<<<dim3(M_ROWS / 128, D_MODEL / 128, 3), 256, 0, stream>>>(
        Qb, Kb, Vb, Wqb, Wkb, Wvb, bq, bk, bv, qh, kh, vh);
    attn_kernel<<<dim3(S_LEN / 128, BATCH * NHEADS), 512, 0, stream>>>(
        qh, kh, vh, mtab, ah);
    out_gemm<<<dim3(M_ROWS / 128, D_MODEL / 128), 256, 0, stream>>>(
        ah, Wob, bo, out);
}